// Round 1
// baseline (2270.386 us; speedup 1.0000x reference)
//
#include <hip/hip_runtime.h>
#include <hip/hip_bf16.h>
#include <cstdint>

// out = softmax((A@J + B) * (1/sqrt(S)) + mask) @ P
// A,J,B,P: [64][1024][1024] fp32;  mask: [1024][1024] fp32;  out fp32.
// Fused flash-style implementation: one block = 32-row i-strip, full softmax row.

typedef __bf16 bf16x8 __attribute__((ext_vector_type(8)));
typedef __bf16 bf16x4 __attribute__((ext_vector_type(4)));
typedef float f32x4 __attribute__((ext_vector_type(4)));

static constexpr int SS = 1024;        // sequence length
static constexpr int BH = 64;          // batch*heads
static constexpr size_t SLICE = (size_t)SS * SS;

// ---- 32x32 tiled transpose + cast: out[bh][c][r] = (bf16)in[bh][r][c] (verified) ----
__global__ __launch_bounds__(256) void transpose_cast(const float* __restrict__ in,
                                                      __bf16* __restrict__ out) {
    __shared__ float tile[32][33];
    const int bh = blockIdx.z;
    const int r0 = blockIdx.y * 32, c0 = blockIdx.x * 32;
    const int t = threadIdx.x;
    const int tr = t >> 3, tc4 = (t & 7) * 4;
    const float4 v = *(const float4*)(in + (size_t)bh * SLICE + (size_t)(r0 + tr) * SS + c0 + tc4);
    tile[tr][tc4 + 0] = v.x;
    tile[tr][tc4 + 1] = v.y;
    tile[tr][tc4 + 2] = v.z;
    tile[tr][tc4 + 3] = v.w;
    __syncthreads();
    const int oc = t >> 3;           // column (becomes output row)
    const int orr = (t & 7) * 4;     // 4 consecutive original rows (output cols)
    bf16x4 o = {(__bf16)tile[orr + 0][oc], (__bf16)tile[orr + 1][oc],
                (__bf16)tile[orr + 2][oc], (__bf16)tile[orr + 3][oc]};
    *(bf16x4*)(out + (size_t)bh * SLICE + (size_t)(c0 + oc) * SS + r0 + orr) = o;
}

// ---- fused: per block = one bh, one 32-row i-strip, all 1024 cols ----
// 8 waves (512 thr). Wave w owns j/n strip [w*128, w*128+128).
// LDS tile [32][1024] bf16 (XOR-swizzled rows): A-strip in phase 1, attn in phase 3.
__global__ __launch_bounds__(512, 2) void fused_attn(
    const float* __restrict__ A, const __bf16* __restrict__ Jt,
    const float* __restrict__ Bm, const __bf16* __restrict__ Pt,
    const float* __restrict__ mask, float* __restrict__ out) {

    __shared__ __align__(16) char smem[64 * 1024 + 2048];
    float* statM = (float*)(smem + 64 * 1024);   // [8 waves][32 rows]
    float* statS = statM + 256;                  // [8 waves][32 rows]

    // XCD-chunk swizzle: dispatch slots raw%8==r land on XCD r; give XCD r a
    // contiguous lid chunk so all 32 i-strips of one bh co-reside per XCD L2.
    const int raw = (int)blockIdx.x;
    const int lid = (raw & 7) * 256 + (raw >> 3);   // 2048 = 8*256, bijective
    const int bh  = lid >> 5;
    const int i0  = (lid & 31) * 32;
    const size_t bhoff = (size_t)bh * SLICE;

    const int tid  = threadIdx.x;
    const int lane = tid & 63, w = tid >> 6;
    const int l16  = lane & 15, l4 = lane >> 4;
    const int jw   = w * 128;
    const int sw   = (l16 & 7) << 4;   // frag-read swizzle (rows l16 and l16+16 share it)

    // ---- stage A strip [32][1024] fp32 -> bf16 LDS, row-XOR-swizzled ----
    {
        const float* Ab = A + bhoff + (size_t)i0 * SS;   // contiguous 32*1024 floats
#pragma unroll
        for (int c = 0; c < 16; ++c) {
            const int elem = c * 2048 + tid * 4;
            const int row = elem >> 10;
            const int colb = (elem & 1023) * 2;
            const float4 v = *(const float4*)(Ab + elem);
            bf16x4 o = {(__bf16)v.x, (__bf16)v.y, (__bf16)v.z, (__bf16)v.w};
            *(bf16x4*)(smem + row * 2048 + (colb ^ ((row & 7) << 4))) = o;
        }
    }
    __syncthreads();   // barrier 1: A-strip visible

    // ---- phase 1: S-strip = A @ J   (no barriers; J frags direct from L2) ----
    f32x4 acc[2][8] = {};
    {
        const __bf16* Jg = Jt + bhoff + (size_t)(jw + l16) * SS + l4 * 8;
        const char* a0 = smem + l16 * 2048;
        const char* a1 = smem + (16 + l16) * 2048;
#pragma unroll 2
        for (int kt = 0; kt < 32; ++kt) {
            bf16x8 bfr[8];
#pragma unroll
            for (int ni = 0; ni < 8; ++ni)
                bfr[ni] = *(const bf16x8*)(Jg + (size_t)ni * 16 * SS + kt * 32);
            const int ko = (kt * 64 + l4 * 16) ^ sw;
            bf16x8 af0 = *(const bf16x8*)(a0 + ko);
            bf16x8 af1 = *(const bf16x8*)(a1 + ko);
#pragma unroll
            for (int ni = 0; ni < 8; ++ni) {
                acc[0][ni] = __builtin_amdgcn_mfma_f32_16x16x32_bf16(af0, bfr[ni], acc[0][ni], 0, 0, 0);
                acc[1][ni] = __builtin_amdgcn_mfma_f32_16x16x32_bf16(af1, bfr[ni], acc[1][ni], 0, 0, 0);
            }
        }
    }

    // ---- bias + scale + mask, local row max ----
    const float scl = 0.03125f;   // 1/sqrt(1024)
    float rm[2][4];
#pragma unroll
    for (int mi = 0; mi < 2; ++mi)
#pragma unroll
        for (int r = 0; r < 4; ++r) rm[mi][r] = -3.4e38f;
#pragma unroll
    for (int mi = 0; mi < 2; ++mi) {
#pragma unroll
        for (int r = 0; r < 4; ++r) {
            const int ig = i0 + mi * 16 + l4 * 4 + r;
#pragma unroll
            for (int ni = 0; ni < 8; ++ni) {
                const int jg = jw + ni * 16 + l16;
                float v = (acc[mi][ni][r] + Bm[bhoff + (size_t)ig * SS + jg]) * scl
                          + mask[(size_t)ig * SS + jg];
                acc[mi][ni][r] = v;
                rm[mi][r] = fmaxf(rm[mi][r], v);
            }
        }
    }
    // reduce max over the 16-lane group (j within wave strip)
#pragma unroll
    for (int mi = 0; mi < 2; ++mi)
#pragma unroll
        for (int r = 0; r < 4; ++r) {
            float m = rm[mi][r];
            m = fmaxf(m, __shfl_xor(m, 1));
            m = fmaxf(m, __shfl_xor(m, 2));
            m = fmaxf(m, __shfl_xor(m, 4));
            m = fmaxf(m, __shfl_xor(m, 8));
            rm[mi][r] = m;
        }
    if (l16 == 0) {
#pragma unroll
        for (int mi = 0; mi < 2; ++mi)
#pragma unroll
            for (int r = 0; r < 4; ++r)
                statM[w * 32 + mi * 16 + l4 * 4 + r] = rm[mi][r];
    }
    __syncthreads();   // barrier 2: row maxima visible; A-strip now dead

    float gm[2][4], ls[2][4];
#pragma unroll
    for (int mi = 0; mi < 2; ++mi)
#pragma unroll
        for (int r = 0; r < 4; ++r) {
            const int rowi = mi * 16 + l4 * 4 + r;
            float g = statM[rowi];
#pragma unroll
            for (int ww = 1; ww < 8; ++ww) g = fmaxf(g, statM[ww * 32 + rowi]);
            gm[mi][r] = g;
            ls[mi][r] = 0.f;
        }

    // exp (unnormalized), accumulate local denom, write bf16 attn into LDS tile
#pragma unroll
    for (int mi = 0; mi < 2; ++mi) {
#pragma unroll
        for (int r = 0; r < 4; ++r) {
            const int rowi = mi * 16 + l4 * 4 + r;
            const int swr = (rowi & 7) << 4;
#pragma unroll
            for (int ni = 0; ni < 8; ++ni) {
                const int jl = jw + ni * 16 + l16;
                float e = __expf(acc[mi][ni][r] - gm[mi][r]);
                ls[mi][r] += e;
                *(__bf16*)(smem + rowi * 2048 + ((jl * 2) ^ swr)) = (__bf16)e;
            }
        }
    }
#pragma unroll
    for (int mi = 0; mi < 2; ++mi)
#pragma unroll
        for (int r = 0; r < 4; ++r) {
            float s = ls[mi][r];
            s += __shfl_xor(s, 1);
            s += __shfl_xor(s, 2);
            s += __shfl_xor(s, 4);
            s += __shfl_xor(s, 8);
            ls[mi][r] = s;
        }
    if (l16 == 0) {
#pragma unroll
        for (int mi = 0; mi < 2; ++mi)
#pragma unroll
            for (int r = 0; r < 4; ++r)
                statS[w * 32 + mi * 16 + l4 * 4 + r] = ls[mi][r];
    }
    __syncthreads();   // barrier 3: attn tile + denominators visible

    float inv[2][4];
#pragma unroll
    for (int mi = 0; mi < 2; ++mi)
#pragma unroll
        for (int r = 0; r < 4; ++r) {
            const int rowi = mi * 16 + l4 * 4 + r;
            float s = statS[rowi];
#pragma unroll
            for (int ww = 1; ww < 8; ++ww) s += statS[ww * 32 + rowi];
            inv[mi][r] = 1.0f / s;
        }

    // ---- phase 3: O-strip = attn @ P  (attn from LDS, P^T frags from L2) ----
    f32x4 oac[2][8] = {};
    {
        const __bf16* Pg = Pt + bhoff + (size_t)(jw + l16) * SS + l4 * 8;
        const char* a0 = smem + l16 * 2048;
        const char* a1 = smem + (16 + l16) * 2048;
#pragma unroll 2
        for (int kt = 0; kt < 32; ++kt) {
            bf16x8 pfr[8];
#pragma unroll
            for (int ni = 0; ni < 8; ++ni)
                pfr[ni] = *(const bf16x8*)(Pg + (size_t)ni * 16 * SS + kt * 32);
            const int ko = (kt * 64 + l4 * 16) ^ sw;
            bf16x8 af0 = *(const bf16x8*)(a0 + ko);
            bf16x8 af1 = *(const bf16x8*)(a1 + ko);
#pragma unroll
            for (int ni = 0; ni < 8; ++ni) {
                oac[0][ni] = __builtin_amdgcn_mfma_f32_16x16x32_bf16(af0, pfr[ni], oac[0][ni], 0, 0, 0);
                oac[1][ni] = __builtin_amdgcn_mfma_f32_16x16x32_bf16(af1, pfr[ni], oac[1][ni], 0, 0, 0);
            }
        }
    }

    // ---- epilogue: normalize by row denom, fp32 store ----
#pragma unroll
    for (int mi = 0; mi < 2; ++mi)
#pragma unroll
        for (int r = 0; r < 4; ++r) {
            const int ig = i0 + mi * 16 + l4 * 4 + r;
#pragma unroll
            for (int ni = 0; ni < 8; ++ni) {
                const int ng = jw + ni * 16 + l16;
                out[bhoff + (size_t)ig * SS + ng] = oac[mi][ni][r] * inv[mi][r];
            }
        }
}

extern "C" void kernel_launch(void* const* d_in, const int* in_sizes, int n_in,
                              void* d_out, int out_size, void* d_ws, size_t ws_size,
                              hipStream_t stream) {
    const float* A    = (const float*)d_in[0];
    const float* J    = (const float*)d_in[1];
    const float* Bm   = (const float*)d_in[2];
    const float* P    = (const float*)d_in[3];
    const float* mask = (const float*)d_in[4];
    float* out = (float*)d_out;

    char* ws = (char*)d_ws;
    const size_t MB128 = (size_t)128 * 1024 * 1024;
    __bf16* Jt = (__bf16*)ws;              // 128 MiB
    __bf16* Pt = (__bf16*)(ws + MB128);    // 128 MiB

    transpose_cast<<<dim3(32, 32, BH), dim3(256), 0, stream>>>(J, Jt);
    transpose_cast<<<dim3(32, 32, BH), dim3(256), 0, stream>>>(P, Pt);
    fused_attn<<<dim3(BH * 32), dim3(512), 0, stream>>>(A, Jt, Bm, Pt, mask, out);
}